// Round 1
// 1118.846 us; speedup vs baseline: 1.1693x; 1.1693x over previous
//
#include <hip/hip_runtime.h>
#include <cmath>

typedef short short8 __attribute__((ext_vector_type(8)));
typedef float floatx4 __attribute__((ext_vector_type(4)));
typedef unsigned short ushortx4 __attribute__((ext_vector_type(4)));

__device__ inline float bf2f(unsigned short u) {
  return __uint_as_float(((unsigned)u) << 16);
}
__device__ inline unsigned short f2bf(float x) {
  unsigned u = __float_as_uint(x);
  u = (u + 0x7FFFu + ((u >> 16) & 1u)) >> 16;
  return (unsigned short)u;
}

// ---------------- dtype probe: bf16 vs fp32 inputs ----------------
__global__ void probe_kernel(const unsigned short* __restrict__ in, int* __restrict__ flag) {
  __shared__ float red[256];
  float m = 0.f;
  for (int i = threadIdx.x; i < 8192; i += 256) {
    float v = fabsf(bf2f(in[i]));
    if (!isnan(v)) m = fmaxf(m, v);
  }
  red[threadIdx.x] = m;
  __syncthreads();
  for (int s = 128; s > 0; s >>= 1) {
    if (threadIdx.x < s) red[threadIdx.x] = fmaxf(red[threadIdx.x], red[threadIdx.x + s]);
    __syncthreads();
  }
  if (threadIdx.x == 0) flag[0] = (red[0] < 1000.0f) ? 1 : 0;  // 1 = input is bf16
}

// ---------------- cast X -> bf16 (or copy) ----------------
__global__ __launch_bounds__(256) void cast_any(const void* __restrict__ in,
                                                unsigned short* __restrict__ out,
                                                const int* __restrict__ flag, int n) {
  int i = (blockIdx.x * 256 + threadIdx.x) * 4;
  if (i >= n) return;
  if (flag[0]) {
    *(ushortx4*)(out + i) = *(const ushortx4*)((const unsigned short*)in + i);
  } else {
    const float* f = (const float*)in + i;
    ushortx4 o;
    o.x = f2bf(f[0]); o.y = f2bf(f[1]); o.z = f2bf(f[2]); o.w = f2bf(f[3]);
    *(ushortx4*)(out + i) = o;
  }
}

// ---------------- transpose+cast W (K=4096 x N) -> WT[n][k] bf16 ----------------
__global__ __launch_bounds__(256) void transpose_cast(const void* __restrict__ W,
                                                      unsigned short* __restrict__ WT,
                                                      const int* __restrict__ flag,
                                                      int N, int rowOff) {
  __shared__ unsigned short tile[32][33];
  int n0 = blockIdx.x * 32, k0 = blockIdx.y * 32;
  int tx = threadIdx.x & 31, ty = threadIdx.x >> 5;
  bool isbf = flag[0] != 0;
#pragma unroll
  for (int p = 0; p < 4; ++p) {
    int k = k0 + ty + p * 8;
    size_t idx = (size_t)k * N + n0 + tx;
    unsigned short b = isbf ? ((const unsigned short*)W)[idx] : f2bf(((const float*)W)[idx]);
    tile[ty + p * 8][tx] = b;
  }
  __syncthreads();
#pragma unroll
  for (int p = 0; p < 4; ++p) {
    int n = n0 + ty + p * 8;
    WT[(size_t)(rowOff + n) * 4096 + k0 + tx] = tile[tx][ty + p * 8];
  }
}

// ---------------- async global->LDS, 16B per lane ----------------
__device__ inline void gload16(const unsigned short* g, unsigned short* lds) {
  __builtin_amdgcn_global_load_lds(
      (const __attribute__((address_space(1))) unsigned int*)g,
      (__attribute__((address_space(3))) unsigned int*)lds, 16, 0, 0);
}

// ================= 256x256 deep-pipelined bf16 MFMA GEMM =================
// C[M,N] = A[M,K] * BT[N,K]^T.  BK=32, triple-buffered LDS, staging 2 K-tiles
// ahead, counted vmcnt(4) at tile boundaries (never 0 in main loop), raw
// s_barrier (NOT __syncthreads -> would drain vmcnt), setprio around MFMA
// clusters, XOR-swizzled LDS via pre-swizzled global source (global_load_lds
// writes linearly; swizzle applied identically on the read side).
// 512 threads = 8 waves (2M x 4N), per-wave 128x64 output = acc[8][4].
template <int OUTMODE>  // 0: bf16 out; 1: flag-selected (bf16 if flag else fp32)
__global__ __launch_bounds__(512, 2) void gemm256(const unsigned short* __restrict__ A,
                                                  const unsigned short* __restrict__ BT,
                                                  void* __restrict__ C, int M, int N, int K,
                                                  int nbn, const int* __restrict__ flag) {
  __shared__ __attribute__((aligned(16))) unsigned short As[3][256 * 32];
  __shared__ __attribute__((aligned(16))) unsigned short Bs[3][256 * 32];
  int tid = threadIdx.x;
  int w = tid >> 6, l = tid & 63;
  int wm = w >> 2, wn = w & 3;  // 2 x 4 wave grid

  // XCD-aware bijective block swizzle (gridDim.x % 8 == 0 for all our shapes)
  int nwg = gridDim.x;
  int cpx = nwg >> 3;
  int bid = blockIdx.x;
  int swz = (bid & 7) * cpx + (bid >> 3);
  int bm = swz / nbn, bn = swz - bm * nbn;
  int m0 = bm * 256, n0 = bn * 256;

  // ---- staging addressing: 512 thr x 16B = 8KB = 128 rows x 64B per issue.
  // LDS dest is linear (wave base + lane*16).  To realize stored[r][c] =
  // orig[r][c ^ f(r)] with f(r) = (r>>1)&3, pre-swizzle the GLOBAL source.
  int sr = tid >> 2;                 // row 0..127 within a 128-row half
  int sc = tid & 3;                  // 16B chunk 0..3
  int sf = (sr >> 1) & 3;            // swizzle key (p*128 preserves it: p*64 % 4 == 0)
  int scs = (sc ^ sf) * 8;           // source element offset within the 32-elem row
  const unsigned short* Ab = A + (size_t)(m0 + sr) * K + scs;
  const unsigned short* Bb = BT + (size_t)(n0 + sr) * K + scs;

  // ---- read addressing: A-frag lane l -> row base+(l&15), k-chunk q=(l>>4).
  // Stored chunk = q ^ ((row>>1)&3) = q ^ (((l&15)>>1)&3): per-lane constant.
  int lane15 = l & 15, q = l >> 4;
  int fl = (lane15 >> 1) & 3;
  int rswz = (q ^ fl) * 8;
  int aoff = (wm * 128 + lane15) * 32 + rswz;
  int boff = (wn * 64 + lane15) * 32 + rswz;

  floatx4 acc[8][4] = {};
  int NT = K >> 5;  // 128 for K=4096

  auto stage_half = [&](int tt, int b, int p) {
    gload16(Ab + (size_t)p * 128 * K + (size_t)tt * 32, &As[b][(p * 128 + w * 16) * 32]);
    gload16(Bb + (size_t)p * 128 * K + (size_t)tt * 32, &Bs[b][(p * 128 + w * 16) * 32]);
  };

  // prologue: stage tiles 0 and 1 (8 vmem ops per wave outstanding)
  stage_half(0, 0, 0);
  stage_half(0, 0, 1);
  stage_half(1, 1, 0);
  stage_half(1, 1, 1);

  int cur = 0;
  for (int t = 0; t < NT; ++t) {
    int nxt2 = cur + 2;
    if (nxt2 >= 3) nxt2 -= 3;        // buffer for tile t+2
    bool pf = (t + 2 < NT);
    // Boundary wait: outstanding = tiles t (oldest 4) + t+1 (4). Retire tile t.
    if (t < NT - 1) asm volatile("s_waitcnt vmcnt(4)" ::: "memory");
    else            asm volatile("s_waitcnt vmcnt(0)" ::: "memory");
    __builtin_amdgcn_s_barrier();

    const unsigned short* pA = &As[cur][0];
    const unsigned short* pB = &Bs[cur][0];

    // ---- phase A: frags (B all 4, A rows 0..63), stage half 0 of tile t+2
    short8 bfr[4], af[4];
#pragma unroll
    for (int i = 0; i < 4; ++i) bfr[i] = *(const short8*)(pB + boff + i * 512);
#pragma unroll
    for (int i = 0; i < 4; ++i) af[i] = *(const short8*)(pA + aoff + i * 512);
    if (pf) stage_half(t + 2, nxt2, 0);
    __builtin_amdgcn_s_barrier();
    __builtin_amdgcn_s_setprio(1);
#pragma unroll
    for (int mi = 0; mi < 4; ++mi)
#pragma unroll
      for (int ni = 0; ni < 4; ++ni)
        acc[mi][ni] = __builtin_amdgcn_mfma_f32_16x16x32_bf16(af[mi], bfr[ni], acc[mi][ni], 0, 0, 0);
    __builtin_amdgcn_s_setprio(0);
    __builtin_amdgcn_s_barrier();

    // ---- phase B: A rows 64..127 (B frags reused from registers), stage half 1
#pragma unroll
    for (int i = 0; i < 4; ++i) af[i] = *(const short8*)(pA + aoff + 2048 + i * 512);
    if (pf) stage_half(t + 2, nxt2, 1);
    __builtin_amdgcn_s_barrier();
    __builtin_amdgcn_s_setprio(1);
#pragma unroll
    for (int mi = 0; mi < 4; ++mi)
#pragma unroll
      for (int ni = 0; ni < 4; ++ni)
        acc[mi + 4][ni] = __builtin_amdgcn_mfma_f32_16x16x32_bf16(af[mi], bfr[ni], acc[mi + 4][ni], 0, 0, 0);
    __builtin_amdgcn_s_setprio(0);

    cur = (cur == 2) ? 0 : cur + 1;
  }

  // ---- epilogue: C[row = m0+wm*128+mi*16+q*4+rr][col = n0+wn*64+ni*16+lane15]
  bool obf = true;
  if (OUTMODE == 1) obf = (flag[0] != 0);
#pragma unroll
  for (int mi = 0; mi < 8; ++mi) {
    int rbase = m0 + wm * 128 + mi * 16 + q * 4;
#pragma unroll
    for (int ni = 0; ni < 4; ++ni) {
      int col = n0 + wn * 64 + ni * 16 + lane15;
#pragma unroll
      for (int rr = 0; rr < 4; ++rr) {
        float v = acc[mi][ni][rr];
        size_t idx = (size_t)(rbase + rr) * N + col;
        if (OUTMODE == 0 || obf)
          ((unsigned short*)C)[idx] = f2bf(v);
        else
          ((float*)C)[idx] = v;
      }
    }
  }
}

// ---------------- fused RoPE + head-softmax + PV per token ----------------
__global__ __launch_bounds__(256) void attn_kernel(const unsigned short* __restrict__ QKV,
                                                   unsigned short* __restrict__ AO) {
  __shared__ __attribute__((aligned(16))) float qr[32 * 136];
  __shared__ __attribute__((aligned(16))) float kr[8 * 136];
  __shared__ __attribute__((aligned(16))) float vv[8 * 136];
  __shared__ float P[256];
  __shared__ float sn[64], cs[64];
  int r = blockIdx.x;
  int pos = r & 4095;  // r = b*4096 + s
  int t = threadIdx.x;
  const unsigned short* row = QKV + (size_t)r * 6144;

  if (t < 64) {
    double e = pow(10000.0, (double)(2 * (t >> 1)) / 64.0);
    float f = (float)pos * (float)e;
    float s_, c_;
    sincosf(f, &s_, &c_);
    sn[t] = s_;
    cs[t] = c_;
  }
  __syncthreads();

  // K (RoPE'd) and V into LDS: 8 heads x 128
#pragma unroll
  for (int p = 0; p < 4; ++p) {
    int e = t + p * 256;
    int head = e >> 7, d = e & 127;
    float x = bf2f(row[4096 + e]);
    float xp = bf2f(row[4096 + (e ^ 64)]);
    float sg = (d < 64) ? -1.f : 1.f;
    kr[head * 136 + d] = x * cs[d & 63] + sg * xp * sn[d & 63];
    vv[head * 136 + d] = bf2f(row[5120 + e]);
  }
  // Q (RoPE'd) into LDS: 32 heads x 128
#pragma unroll
  for (int p = 0; p < 16; ++p) {
    int e = t + p * 256;
    int head = e >> 7, d = e & 127;
    float x = bf2f(row[e]);
    float xp = bf2f(row[e ^ 64]);
    float sg = (d < 64) ? -1.f : 1.f;
    qr[head * 136 + d] = x * cs[d & 63] + sg * xp * sn[d & 63];
  }
  __syncthreads();

  // scores: thread t -> (h = t>>3, j = t&7)
  int h = t >> 3, j = t & 7;
  const float4* q4 = (const float4*)(qr + h * 136);
  const float4* k4 = (const float4*)(kr + j * 136);
  float s = 0.f;
#pragma unroll
  for (int d4 = 0; d4 < 32; ++d4) {
    float4 a = q4[d4], b = k4[d4];
    s += a.x * b.x + a.y * b.y + a.z * b.z + a.w * b.w;
  }
  s *= 0.08838834764831845f;  // 1/sqrt(128)
  float mx = s;
  mx = fmaxf(mx, __shfl_xor(mx, 1));
  mx = fmaxf(mx, __shfl_xor(mx, 2));
  mx = fmaxf(mx, __shfl_xor(mx, 4));
  float ex = expf(s - mx);
  float sm = ex;
  sm += __shfl_xor(sm, 1);
  sm += __shfl_xor(sm, 2);
  sm += __shfl_xor(sm, 4);
  P[t] = ex / sm;
  __syncthreads();

  // out[h][d0..d0+16) = sum_j P[h][j] * v[j][d]
  int d0 = (t & 7) * 16;
  float o[16];
#pragma unroll
  for (int c = 0; c < 16; ++c) o[c] = 0.f;
#pragma unroll
  for (int j2 = 0; j2 < 8; ++j2) {
    float pj = P[h * 8 + j2];
    const float4* v4 = (const float4*)(vv + j2 * 136 + d0);
#pragma unroll
    for (int c = 0; c < 4; ++c) {
      float4 x = v4[c];
      o[c * 4 + 0] += pj * x.x;
      o[c * 4 + 1] += pj * x.y;
      o[c * 4 + 2] += pj * x.z;
      o[c * 4 + 3] += pj * x.w;
    }
  }
  unsigned short* outp = AO + (size_t)r * 4096 + h * 128 + d0;
#pragma unroll
  for (int c = 0; c < 4; ++c) {
    ushortx4 ov;
    ov.x = f2bf(o[c * 4 + 0]);
    ov.y = f2bf(o[c * 4 + 1]);
    ov.z = f2bf(o[c * 4 + 2]);
    ov.w = f2bf(o[c * 4 + 3]);
    *(ushortx4*)(outp + c * 4) = ov;
  }
}

extern "C" void kernel_launch(void* const* d_in, const int* in_sizes, int n_in,
                              void* d_out, int out_size, void* d_ws, size_t ws_size,
                              hipStream_t stream) {
  (void)in_sizes; (void)n_in; (void)out_size; (void)ws_size;
  const void* X  = d_in[0];
  const void* Wq = d_in[1];
  const void* Wk = d_in[2];
  const void* Wv = d_in[3];
  const void* Wo = d_in[4];
  char* ws = (char*)d_ws;
  unsigned short* Xb   = (unsigned short*)(ws);                 // 8192x4096 bf16
  unsigned short* WT   = (unsigned short*)(ws + 67108864);      // 6144x4096 bf16 (Wq|Wk|Wv)^T
  unsigned short* WoT  = (unsigned short*)(ws + 117440512);     // 4096x4096 bf16
  unsigned short* QKVb = (unsigned short*)(ws + 150994944);     // 8192x6144 bf16
  int* flag            = (int*)(ws + 251658240);
  unsigned short* AO = Xb;  // alias: Xb dead after gemm1

  probe_kernel<<<1, 256, 0, stream>>>((const unsigned short*)X, flag);
  cast_any<<<32768, 256, 0, stream>>>(X, Xb, flag, 33554432);
  transpose_cast<<<dim3(128, 128), 256, 0, stream>>>(Wq, WT, flag, 4096, 0);
  transpose_cast<<<dim3(32, 128), 256, 0, stream>>>(Wk, WT, flag, 1024, 4096);
  transpose_cast<<<dim3(32, 128), 256, 0, stream>>>(Wv, WT, flag, 1024, 5120);
  transpose_cast<<<dim3(128, 128), 256, 0, stream>>>(Wo, WoT, flag, 4096, 0);
  // 256x256 tiles: gemm1 grid 24x32=768 blocks, gemm2 16x32=512 (both %8==0)
  gemm256<0><<<768, 512, 0, stream>>>(Xb, WT, QKVb, 8192, 6144, 4096, 24, flag);
  attn_kernel<<<8192, 256, 0, stream>>>(QKVb, AO);
  gemm256<1><<<512, 512, 0, stream>>>(AO, WoT, d_out, 8192, 4096, 4096, 16, flag);
}

// Round 2
// 1009.232 us; speedup vs baseline: 1.2963x; 1.1086x over previous
//
#include <hip/hip_runtime.h>
#include <cmath>

typedef short short8 __attribute__((ext_vector_type(8)));
typedef float floatx4 __attribute__((ext_vector_type(4)));
typedef unsigned short ushortx4 __attribute__((ext_vector_type(4)));

__device__ inline float bf2f(unsigned short u) {
  return __uint_as_float(((unsigned)u) << 16);
}
__device__ inline unsigned short f2bf(float x) {
  unsigned u = __float_as_uint(x);
  u = (u + 0x7FFFu + ((u >> 16) & 1u)) >> 16;
  return (unsigned short)u;
}

// ---------------- dtype probe: bf16 vs fp32 inputs ----------------
__global__ void probe_kernel(const unsigned short* __restrict__ in, int* __restrict__ flag) {
  __shared__ float red[256];
  float m = 0.f;
  for (int i = threadIdx.x; i < 8192; i += 256) {
    float v = fabsf(bf2f(in[i]));
    if (!isnan(v)) m = fmaxf(m, v);
  }
  red[threadIdx.x] = m;
  __syncthreads();
  for (int s = 128; s > 0; s >>= 1) {
    if (threadIdx.x < s) red[threadIdx.x] = fmaxf(red[threadIdx.x], red[threadIdx.x + s]);
    __syncthreads();
  }
  if (threadIdx.x == 0) flag[0] = (red[0] < 1000.0f) ? 1 : 0;  // 1 = input is bf16
}

// ---------------- cast X -> bf16 (or copy) ----------------
__global__ __launch_bounds__(256) void cast_any(const void* __restrict__ in,
                                                unsigned short* __restrict__ out,
                                                const int* __restrict__ flag, int n) {
  int i = (blockIdx.x * 256 + threadIdx.x) * 4;
  if (i >= n) return;
  if (flag[0]) {
    *(ushortx4*)(out + i) = *(const ushortx4*)((const unsigned short*)in + i);
  } else {
    const float* f = (const float*)in + i;
    ushortx4 o;
    o.x = f2bf(f[0]); o.y = f2bf(f[1]); o.z = f2bf(f[2]); o.w = f2bf(f[3]);
    *(ushortx4*)(out + i) = o;
  }
}

// ---------------- transpose+cast W (K=4096 x N) -> WT[n][k] bf16 ----------------
__global__ __launch_bounds__(256) void transpose_cast(const void* __restrict__ W,
                                                      unsigned short* __restrict__ WT,
                                                      const int* __restrict__ flag,
                                                      int N, int rowOff) {
  __shared__ unsigned short tile[32][33];
  int n0 = blockIdx.x * 32, k0 = blockIdx.y * 32;
  int tx = threadIdx.x & 31, ty = threadIdx.x >> 5;
  bool isbf = flag[0] != 0;
#pragma unroll
  for (int p = 0; p < 4; ++p) {
    int k = k0 + ty + p * 8;
    size_t idx = (size_t)k * N + n0 + tx;
    unsigned short b = isbf ? ((const unsigned short*)W)[idx] : f2bf(((const float*)W)[idx]);
    tile[ty + p * 8][tx] = b;
  }
  __syncthreads();
#pragma unroll
  for (int p = 0; p < 4; ++p) {
    int n = n0 + ty + p * 8;
    WT[(size_t)(rowOff + n) * 4096 + k0 + tx] = tile[tx][ty + p * 8];
  }
}

// ---------------- async global->LDS, 16B per lane ----------------
__device__ inline void gload16(const unsigned short* g, unsigned short* lds) {
  __builtin_amdgcn_global_load_lds(
      (const __attribute__((address_space(1))) unsigned int*)g,
      (__attribute__((address_space(3))) unsigned int*)lds, 16, 0, 0);
}

// ================= 256x256 deep-pipelined bf16 MFMA GEMM =================
// C[M,N] = A[M,K] * BT[N,K]^T.  BK=32, triple-buffered LDS, staging 2 K-tiles
// ahead.  MERGED tile body: ONE {counted vmcnt; s_barrier} per K-tile, then
// all 12 frag ds_reads + 4 stage issues + 32 MFMA as straight-line code so
// the compiler fine-interleaves lgkmcnt waits with the MFMA run (LDS returns
// hide under ~1030cy of matrix-pipe work instead of barrier-bracketed
// windows).  Correctness: per-wave vmcnt(4)+barrier => all waves' DMAs for
// the tile complete; barrier arrival => prior tile's ds_reads issued before
// any new DMA write can land (>=200cy HBM/L2 latency margin).
template <int OUTMODE>  // 0: bf16 out; 1: flag-selected (bf16 if flag else fp32)
__global__ __launch_bounds__(512, 2) void gemm256(const unsigned short* __restrict__ A,
                                                  const unsigned short* __restrict__ BT,
                                                  void* __restrict__ C, int M, int N, int K,
                                                  int nbn, const int* __restrict__ flag) {
  __shared__ __attribute__((aligned(16))) unsigned short As[3][256 * 32];
  __shared__ __attribute__((aligned(16))) unsigned short Bs[3][256 * 32];
  int tid = threadIdx.x;
  int w = tid >> 6, l = tid & 63;
  int wm = w >> 2, wn = w & 3;  // 2 x 4 wave grid

  // XCD-aware bijective block swizzle (gridDim.x % 8 == 0 for all our shapes)
  int nwg = gridDim.x;
  int cpx = nwg >> 3;
  int bid = blockIdx.x;
  int swz = (bid & 7) * cpx + (bid >> 3);
  int bm = swz / nbn, bn = swz - bm * nbn;
  int m0 = bm * 256, n0 = bn * 256;

  // ---- staging addressing: 512 thr x 16B = 8KB = 128 rows x 64B per issue.
  // stored[r][c] = orig[r][c ^ ((r>>1)&3)] realized by pre-swizzled GLOBAL src.
  int sr = tid >> 2;                 // row 0..127 within a 128-row half
  int sc = tid & 3;                  // 16B chunk 0..3
  int sf = (sr >> 1) & 3;
  int scs = (sc ^ sf) * 8;
  const unsigned short* Ab = A + (size_t)(m0 + sr) * K + scs;
  const unsigned short* Bb = BT + (size_t)(n0 + sr) * K + scs;

  // ---- read addressing: frag lane l -> row base+(l&15), k-chunk q=(l>>4).
  int lane15 = l & 15, q = l >> 4;
  int fl = (lane15 >> 1) & 3;
  int rswz = (q ^ fl) * 8;
  int aoff = (wm * 128 + lane15) * 32 + rswz;
  int boff = (wn * 64 + lane15) * 32 + rswz;

  floatx4 acc[8][4] = {};
  int NT = K >> 5;  // 128 for K=4096

  auto stage_half = [&](int tt, int b, int p) {
    gload16(Ab + (size_t)p * 128 * K + (size_t)tt * 32, &As[b][(p * 128 + w * 16) * 32]);
    gload16(Bb + (size_t)p * 128 * K + (size_t)tt * 32, &Bs[b][(p * 128 + w * 16) * 32]);
  };

  // prologue: stage tiles 0 and 1 (8 vmem ops per wave outstanding)
  stage_half(0, 0, 0);
  stage_half(0, 0, 1);
  stage_half(1, 1, 0);
  stage_half(1, 1, 1);

  int cur = 0;
  for (int t = 0; t < NT; ++t) {
    int nxt2 = cur + 2;
    if (nxt2 >= 3) nxt2 -= 3;        // buffer for tile t+2
    // Boundary wait: outstanding = tiles t (oldest 4) + t+1 (4). Retire tile t.
    if (t < NT - 1) asm volatile("s_waitcnt vmcnt(4)" ::: "memory");
    else            asm volatile("s_waitcnt vmcnt(0)" ::: "memory");
    __builtin_amdgcn_s_barrier();

    const unsigned short* pA = &As[cur][0];
    const unsigned short* pB = &Bs[cur][0];

    // all frag reads up front: B first, then A-half0, then A-half1 (so the
    // first MFMA's lgkm wait leaves the A-half1 reads still in flight)
    short8 bfr[4], afA[4], afB[4];
#pragma unroll
    for (int i = 0; i < 4; ++i) bfr[i] = *(const short8*)(pB + boff + i * 512);
#pragma unroll
    for (int i = 0; i < 4; ++i) afA[i] = *(const short8*)(pA + aoff + i * 512);
#pragma unroll
    for (int i = 0; i < 4; ++i) afB[i] = *(const short8*)(pA + aoff + 2048 + i * 512);

    if (t + 2 < NT) {
      stage_half(t + 2, nxt2, 0);
      stage_half(t + 2, nxt2, 1);
    }

    __builtin_amdgcn_s_setprio(1);
#pragma unroll
    for (int mi = 0; mi < 4; ++mi)
#pragma unroll
      for (int ni = 0; ni < 4; ++ni)
        acc[mi][ni] = __builtin_amdgcn_mfma_f32_16x16x32_bf16(afA[mi], bfr[ni], acc[mi][ni], 0, 0, 0);
#pragma unroll
    for (int mi = 0; mi < 4; ++mi)
#pragma unroll
      for (int ni = 0; ni < 4; ++ni)
        acc[mi + 4][ni] = __builtin_amdgcn_mfma_f32_16x16x32_bf16(afB[mi], bfr[ni], acc[mi + 4][ni], 0, 0, 0);
    __builtin_amdgcn_s_setprio(0);

    cur = (cur == 2) ? 0 : cur + 1;
  }

  // ---- epilogue: C[row = m0+wm*128+mi*16+q*4+rr][col = n0+wn*64+ni*16+lane15]
  bool obf = true;
  if (OUTMODE == 1) obf = (flag[0] != 0);
#pragma unroll
  for (int mi = 0; mi < 8; ++mi) {
    int rbase = m0 + wm * 128 + mi * 16 + q * 4;
#pragma unroll
    for (int ni = 0; ni < 4; ++ni) {
      int col = n0 + wn * 64 + ni * 16 + lane15;
#pragma unroll
      for (int rr = 0; rr < 4; ++rr) {
        float v = acc[mi][ni][rr];
        size_t idx = (size_t)(rbase + rr) * N + col;
        if (OUTMODE == 0 || obf)
          ((unsigned short*)C)[idx] = f2bf(v);
        else
          ((float*)C)[idx] = v;
      }
    }
  }
}

// ---------------- RoPE sin/cos table: tab[pos][i] = {sin,cos} ----------------
__global__ __launch_bounds__(256) void rope_tab(float* __restrict__ tab) {
  int i = blockIdx.x * 256 + threadIdx.x;  // over 4096*64
  int pos = i >> 6, k = i & 63;
  double e = pow(10000.0, (double)(2 * (k >> 1)) / 64.0);
  float f = (float)pos * (float)e;
  float s_, c_;
  sincosf(f, &s_, &c_);
  tab[i * 2] = s_;
  tab[i * 2 + 1] = c_;
}

// ---------------- fused RoPE + head-softmax + PV per token ----------------
__global__ __launch_bounds__(256) void attn_kernel(const unsigned short* __restrict__ QKV,
                                                   const float* __restrict__ tab,
                                                   unsigned short* __restrict__ AO) {
  __shared__ __attribute__((aligned(16))) float qr[32 * 140];
  __shared__ __attribute__((aligned(16))) float kr[8 * 140];
  __shared__ __attribute__((aligned(16))) float vv[8 * 140];
  __shared__ float P[256];
  __shared__ float sn[64], cs[64];
  int r = blockIdx.x;
  int pos = r & 4095;  // r = b*4096 + s
  int t = threadIdx.x;
  const unsigned short* row = QKV + (size_t)r * 6144;

  if (t < 64) {
    const float2* t2 = (const float2*)tab + (size_t)pos * 64 + t;
    float2 sc = *t2;
    sn[t] = sc.x;
    cs[t] = sc.y;
  }
  __syncthreads();

  // K (RoPE'd) and V into LDS: 8 heads x 128
#pragma unroll
  for (int p = 0; p < 4; ++p) {
    int e = t + p * 256;
    int head = e >> 7, d = e & 127;
    float x = bf2f(row[4096 + e]);
    float xp = bf2f(row[4096 + (e ^ 64)]);
    float sg = (d < 64) ? -1.f : 1.f;
    kr[head * 140 + d] = x * cs[d & 63] + sg * xp * sn[d & 63];
    vv[head * 140 + d] = bf2f(row[5120 + e]);
  }
  // Q (RoPE'd) into LDS: 32 heads x 128
#pragma unroll
  for (int p = 0; p < 16; ++p) {
    int e = t + p * 256;
    int head = e >> 7, d = e & 127;
    float x = bf2f(row[e]);
    float xp = bf2f(row[e ^ 64]);
    float sg = (d < 64) ? -1.f : 1.f;
    qr[head * 140 + d] = x * cs[d & 63] + sg * xp * sn[d & 63];
  }
  __syncthreads();

  // scores: thread t -> (h = t>>3, j = t&7); stride 140 => distinct-row
  // accesses hit distinct bank groups (12h mod 32), same-row broadcasts free
  int h = t >> 3, j = t & 7;
  const float4* q4 = (const float4*)(qr + h * 140);
  const float4* k4 = (const float4*)(kr + j * 140);
  float s = 0.f;
#pragma unroll
  for (int d4 = 0; d4 < 32; ++d4) {
    float4 a = q4[d4], b = k4[d4];
    s += a.x * b.x + a.y * b.y + a.z * b.z + a.w * b.w;
  }
  s *= 0.08838834764831845f;  // 1/sqrt(128)
  float mx = s;
  mx = fmaxf(mx, __shfl_xor(mx, 1));
  mx = fmaxf(mx, __shfl_xor(mx, 2));
  mx = fmaxf(mx, __shfl_xor(mx, 4));
  float ex = expf(s - mx);
  float sm = ex;
  sm += __shfl_xor(sm, 1);
  sm += __shfl_xor(sm, 2);
  sm += __shfl_xor(sm, 4);
  P[t] = ex / sm;
  __syncthreads();

  // out[h][d0..d0+16) = sum_j P[h][j] * v[j][d]
  int d0 = (t & 7) * 16;
  float o[16];
#pragma unroll
  for (int c = 0; c < 16; ++c) o[c] = 0.f;
#pragma unroll
  for (int j2 = 0; j2 < 8; ++j2) {
    float pj = P[h * 8 + j2];
    const float4* v4 = (const float4*)(vv + j2 * 140 + d0);
#pragma unroll
    for (int c = 0; c < 4; ++c) {
      float4 x = v4[c];
      o[c * 4 + 0] += pj * x.x;
      o[c * 4 + 1] += pj * x.y;
      o[c * 4 + 2] += pj * x.z;
      o[c * 4 + 3] += pj * x.w;
    }
  }
  unsigned short* outp = AO + (size_t)r * 4096 + h * 128 + d0;
#pragma unroll
  for (int c = 0; c < 4; ++c) {
    ushortx4 ov;
    ov.x = f2bf(o[c * 4 + 0]);
    ov.y = f2bf(o[c * 4 + 1]);
    ov.z = f2bf(o[c * 4 + 2]);
    ov.w = f2bf(o[c * 4 + 3]);
    *(ushortx4*)(outp + c * 4) = ov;
  }
}

extern "C" void kernel_launch(void* const* d_in, const int* in_sizes, int n_in,
                              void* d_out, int out_size, void* d_ws, size_t ws_size,
                              hipStream_t stream) {
  (void)in_sizes; (void)n_in; (void)out_size; (void)ws_size;
  const void* X  = d_in[0];
  const void* Wq = d_in[1];
  const void* Wk = d_in[2];
  const void* Wv = d_in[3];
  const void* Wo = d_in[4];
  char* ws = (char*)d_ws;
  unsigned short* Xb   = (unsigned short*)(ws);                 // 8192x4096 bf16
  unsigned short* WT   = (unsigned short*)(ws + 67108864);      // 6144x4096 bf16 (Wq|Wk|Wv)^T
  unsigned short* WoT  = (unsigned short*)(ws + 117440512);     // 4096x4096 bf16
  unsigned short* QKVb = (unsigned short*)(ws + 150994944);     // 8192x6144 bf16
  int* flag            = (int*)(ws + 251658240);
  unsigned short* AO = Xb;  // alias: Xb dead after gemm1
  float* tab = (float*)(ws + 67108864);  // alias: WT dead after gemm1 (2 MB table)

  probe_kernel<<<1, 256, 0, stream>>>((const unsigned short*)X, flag);
  cast_any<<<32768, 256, 0, stream>>>(X, Xb, flag, 33554432);
  transpose_cast<<<dim3(128, 128), 256, 0, stream>>>(Wq, WT, flag, 4096, 0);
  transpose_cast<<<dim3(32, 128), 256, 0, stream>>>(Wk, WT, flag, 1024, 4096);
  transpose_cast<<<dim3(32, 128), 256, 0, stream>>>(Wv, WT, flag, 1024, 5120);
  transpose_cast<<<dim3(128, 128), 256, 0, stream>>>(Wo, WoT, flag, 4096, 0);
  // 256x256 tiles: gemm1 grid 24x32=768 blocks, gemm2 16x32=512 (both %8==0)
  gemm256<0><<<768, 512, 0, stream>>>(Xb, WT, QKVb, 8192, 6144, 4096, 24, flag);
  rope_tab<<<1024, 256, 0, stream>>>(tab);  // WT region is dead now
  attn_kernel<<<8192, 256, 0, stream>>>(QKVb, tab, AO);
  gemm256<1><<<512, 512, 0, stream>>>(AO, WoT, d_out, 8192, 4096, 4096, 16, flag);
}